// Round 1
// 383.900 us; speedup vs baseline: 1.0870x; 1.0870x over previous
//
#include <hip/hip_runtime.h>
#include <hip/hip_bf16.h>
#include <math.h>

// ---------------------------------------------------------------------------
// GCN forward: out = log_softmax( A@( relu(A@(x@W1)+b1) @ W2 ) + b2 )
// Round 5: spmm1 MLP. Previous version had VGPR=32 -> compiler serialized to
// ~1 outstanding gather/wave (vmcnt(0) per edge). Now: 32-edge chunks staged
// in lanes 0-31 (readlane broadcast), next chunk's col/val double-buffered,
// gathers issued in 4 explicit statically-indexed u[8] batches (up to 32 in
// flight before first FMA), zero-padded val kills the serial tail loop.
// spmm2: edge unroll 4 -> 8 (same MLP theory, conservative edit).
// ---------------------------------------------------------------------------

#define GCN_NFEAT 256
#define GCN_NHID  128
#define GCN_NCLASS 40

typedef __bf16 bf16_t;
typedef bf16_t bf16x8 __attribute__((ext_vector_type(8)));
typedef float  f32x4  __attribute__((ext_vector_type(4)));

static __device__ __forceinline__ unsigned short f2b(float f) {
    bf16_t b = (bf16_t)f;
    return *(unsigned short*)&b;
}
static __device__ __forceinline__ float blo(unsigned int u) {
    return __uint_as_float(u << 16);
}
static __device__ __forceinline__ float bhi(unsigned int u) {
    return __uint_as_float(u & 0xffff0000u);
}

// ---- row_ptr[r] = lower_bound(adj_row, r), r in [0, N] ---------------------
__global__ __launch_bounds__(256) void k_row_ptr(
    const int* __restrict__ row, int* __restrict__ row_ptr, int n_rows, int n_edges)
{
    int r = blockIdx.x * blockDim.x + threadIdx.x;
    if (r > n_rows) return;
    int lo = 0, hi = n_edges;
    while (lo < hi) {
        int mid = (lo + hi) >> 1;
        if (row[mid] < r) lo = mid + 1; else hi = mid;
    }
    row_ptr[r] = lo;
}

// ---- prep: W1t_bf16[128][256] = bf16(W1[k][c]) transposed ------------------
__global__ __launch_bounds__(256) void k_prep_w1t(
    const float* __restrict__ w1, bf16_t* __restrict__ w1t)
{
    int idx = blockIdx.x * 256 + threadIdx.x;           // 128*256 total
    int c = idx & 127;
    int k = idx >> 7;
    w1t[(size_t)c * GCN_NFEAT + k] = (bf16_t)w1[(size_t)k * GCN_NHID + c];
}

// ---- prep: W2t_bf16[48][128], cols 40..47 zero -----------------------------
__global__ __launch_bounds__(256) void k_prep_w2t(
    const float* __restrict__ w2, bf16_t* __restrict__ w2t)
{
    int idx = blockIdx.x * 256 + threadIdx.x;           // 48*128 = 6144 total
    if (idx >= 48 * GCN_NHID) return;
    int c = idx / GCN_NHID;
    int k = idx - c * GCN_NHID;
    float v = (c < GCN_NCLASS) ? w2[(size_t)k * GCN_NCLASS + c] : 0.f;
    w2t[idx] = (bf16_t)v;
}

// ---- GEMM1 (MFMA): sup1_bf16[N,128] = bf16( x[N,256] @ W1 ) ----------------
__global__ __launch_bounds__(256) void k_gemm1(
    const float* __restrict__ x, const bf16_t* __restrict__ w1t,
    bf16_t* __restrict__ out, int nrows)
{
    __shared__ __align__(16) bf16_t As[128][72];   // [row][k]
    __shared__ __align__(16) bf16_t Bs[128][72];   // [col][k]

    const int tid  = threadIdx.x;
    const int wave = tid >> 6, lane = tid & 63;
    const int wm = wave >> 1, wn = wave & 1;
    const int lm = lane & 15, quad = lane >> 4;
    const int r0 = blockIdx.x * 128;

    f32x4 acc[4][4] = {};

    for (int k0 = 0; k0 < GCN_NFEAT; k0 += 64) {
        {
            const int row = tid >> 1, half = tid & 1;
            const int gr = r0 + row;
            union { bf16_t b[32]; uint4 q[4]; } t;
            if (gr < nrows) {
                const float* p = x + (size_t)gr * GCN_NFEAT + k0 + half * 32;
#pragma unroll
                for (int i = 0; i < 8; i++) {
                    float4 v = ((const float4*)p)[i];
                    t.b[i*4+0] = (bf16_t)v.x; t.b[i*4+1] = (bf16_t)v.y;
                    t.b[i*4+2] = (bf16_t)v.z; t.b[i*4+3] = (bf16_t)v.w;
                }
            } else {
#pragma unroll
                for (int i = 0; i < 4; i++) t.q[i] = make_uint4(0,0,0,0);
            }
            uint4* dst = (uint4*)&As[row][half * 32];
#pragma unroll
            for (int i = 0; i < 4; i++) dst[i] = t.q[i];
        }
        {
            const int colc = tid >> 1, half = tid & 1;
            const uint4* src = (const uint4*)(w1t + (size_t)colc * GCN_NFEAT + k0 + half * 32);
            uint4* dst = (uint4*)&Bs[colc][half * 32];
#pragma unroll
            for (int i = 0; i < 4; i++) dst[i] = src[i];
        }
        __syncthreads();

#pragma unroll
        for (int ks = 0; ks < 2; ks++) {
            bf16x8 af[4], bfr[4];
#pragma unroll
            for (int i = 0; i < 4; i++)
                af[i] = *(const bf16x8*)&As[wm*64 + i*16 + lm][ks*32 + quad*8];
#pragma unroll
            for (int j = 0; j < 4; j++)
                bfr[j] = *(const bf16x8*)&Bs[wn*64 + j*16 + lm][ks*32 + quad*8];
#pragma unroll
            for (int i = 0; i < 4; i++)
#pragma unroll
                for (int j = 0; j < 4; j++)
                    acc[i][j] = __builtin_amdgcn_mfma_f32_16x16x32_bf16(
                        af[i], bfr[j], acc[i][j], 0, 0, 0);
        }
        __syncthreads();
    }

#pragma unroll
    for (int i = 0; i < 4; i++) {
#pragma unroll
        for (int reg = 0; reg < 4; reg++) {
            const int gr = r0 + wm*64 + i*16 + quad*4 + reg;
            if (gr < nrows) {
#pragma unroll
                for (int j = 0; j < 4; j++) {
                    const int gc = wn*64 + j*16 + lm;
                    out[(size_t)gr * GCN_NHID + gc] = (bf16_t)acc[i][j][reg];
                }
            }
        }
    }
}

// ---- spmm1: h_bf16[r,:] = relu( sum_e val[e]*sup1[col[e],:] + b1 ) ---------
// wave per row. 32-edge chunks staged by lanes 0-31 (zero-padded val past the
// row end), broadcast via v_readlane (compile-time lane idx). Gathers issued
// in 4 statically-indexed u[8] batches BEFORE any FMA -> up to 32 loads in
// flight. Next chunk's col/val loads issued before the FMA phase (dbuf).
#define SPMM1_ISSUE(U, K)                                               \
    _Pragma("unroll")                                                   \
    for (int j = 0; j < 8; j++) {                                       \
        const int cj = __builtin_amdgcn_readlane(cc, (K) + j);          \
        U[j] = sup[((unsigned)cj << 6) + lane];                         \
    }

#define SPMM1_FMA(U, K)                                                 \
    _Pragma("unroll")                                                   \
    for (int j = 0; j < 8; j++) {                                       \
        const float vj = __uint_as_float((unsigned)                     \
            __builtin_amdgcn_readlane((int)__float_as_uint(vc), (K)+j));\
        ax = fmaf(vj, blo(U[j]), ax);                                   \
        ay = fmaf(vj, bhi(U[j]), ay);                                   \
    }

__global__ __launch_bounds__(256) void k_spmm1(
    const int* __restrict__ row_ptr, const int* __restrict__ col,
    const float* __restrict__ val, const unsigned int* __restrict__ sup,
    const float* __restrict__ b1, unsigned int* __restrict__ h, int nrows)
{
    const int wid  = (blockIdx.x * blockDim.x + threadIdx.x) >> 6;
    const int lane = threadIdx.x & 63;
    if (wid >= nrows) return;
    const int e0 = row_ptr[wid];
    const int e1 = row_ptr[wid + 1];
    const int n  = e1 - e0;                 // wave-uniform
    const int sub = lane & 31;

    // stage chunk 0 (zero-padded: val=0 beyond row end makes extra edges no-ops)
    int cv = 0; float vv = 0.f;
    {
        const int idx = e0 + sub;
        const bool ok = idx < e1;
        cv = ok ? col[idx] : 0;
        vv = ok ? val[idx] : 0.f;
    }

    float ax = 0.f, ay = 0.f;

    for (int base = 0; base < n; base += 32) {
        const int   cc = cv;
        const float vc = vv;
        // prefetch next chunk's col/val before the FMA phase
        if (base + 32 < n) {
            const int idx = e0 + base + 32 + sub;
            const bool ok = idx < e1;
            cv = ok ? col[idx] : 0;
            vv = ok ? val[idx] : 0.f;
        }
        const int nb = n - base;            // wave-uniform
        unsigned u0[8], u1[8], u2[8], u3[8];
        SPMM1_ISSUE(u0, 0)
        if (nb > 8)  { SPMM1_ISSUE(u1, 8)  }
        if (nb > 16) { SPMM1_ISSUE(u2, 16) }
        if (nb > 24) { SPMM1_ISSUE(u3, 24) }
        SPMM1_FMA(u0, 0)
        if (nb > 8)  { SPMM1_FMA(u1, 8)  }
        if (nb > 16) { SPMM1_FMA(u2, 16) }
        if (nb > 24) { SPMM1_FMA(u3, 24) }
    }

    const float2 bb = *(const float2*)(b1 + lane * 2);
    const float ox = fmaxf(ax + bb.x, 0.f);
    const float oy = fmaxf(ay + bb.y, 0.f);
    h[(unsigned)(wid << 6) + lane] = (unsigned int)f2b(ox) | ((unsigned int)f2b(oy) << 16);
}

// ---- GEMM2 (MFMA): sup2_bf16[N,40] = bf16( h[N,128] @ W2 ) -----------------
__global__ __launch_bounds__(256) void k_gemm2(
    const bf16_t* __restrict__ h, const bf16_t* __restrict__ w2t,
    bf16_t* __restrict__ out, int nrows)
{
    __shared__ __align__(16) bf16_t As[128][136];  // [row][k]
    __shared__ __align__(16) bf16_t Bs[48][136];   // [col][k]

    const int tid  = threadIdx.x;
    const int wave = tid >> 6, lane = tid & 63;
    const int lm = lane & 15, quad = lane >> 4;
    const int r0 = blockIdx.x * 128;

    {
        const int row = tid >> 1, half = tid & 1;
        const int gr = r0 + row;
        uint4* dst = (uint4*)&As[row][half * 64];
        if (gr < nrows) {
            const uint4* src = (const uint4*)(h + (size_t)gr * GCN_NHID + half * 64);
#pragma unroll
            for (int i = 0; i < 8; i++) dst[i] = src[i];
        } else {
#pragma unroll
            for (int i = 0; i < 8; i++) dst[i] = make_uint4(0,0,0,0);
        }
    }
    // stage B: 48 rows x 16 uint4 (full 256 B row)
    for (int idx = tid; idx < 48 * 16; idx += 256) {
        const int c = idx >> 4, seg = idx & 15;
        ((uint4*)&Bs[c][0])[seg] = ((const uint4*)(w2t + (size_t)c * GCN_NHID))[seg];
    }
    __syncthreads();

    f32x4 acc[2][3] = {};
#pragma unroll
    for (int ks = 0; ks < 4; ks++) {
        bf16x8 af[2], bfr[3];
#pragma unroll
        for (int i = 0; i < 2; i++)
            af[i] = *(const bf16x8*)&As[wave*32 + i*16 + lm][ks*32 + quad*8];
#pragma unroll
        for (int j = 0; j < 3; j++)
            bfr[j] = *(const bf16x8*)&Bs[j*16 + lm][ks*32 + quad*8];
#pragma unroll
        for (int i = 0; i < 2; i++)
#pragma unroll
            for (int j = 0; j < 3; j++)
                acc[i][j] = __builtin_amdgcn_mfma_f32_16x16x32_bf16(
                    af[i], bfr[j], acc[i][j], 0, 0, 0);
    }

#pragma unroll
    for (int i = 0; i < 2; i++) {
#pragma unroll
        for (int reg = 0; reg < 4; reg++) {
            const int gr = r0 + wave*32 + i*16 + quad*4 + reg;
            if (gr < nrows) {
#pragma unroll
                for (int j = 0; j < 3; j++) {
                    const int gc = j*16 + lm;
                    if (gc < GCN_NCLASS)
                        out[(size_t)gr * GCN_NCLASS + gc] = (bf16_t)acc[i][j][reg];
                }
            }
        }
    }
}

// ---- spmm2 + bias + log_softmax -> out[N,40] fp32 --------------------------
// 3 rows per wave: group g = lane/20 handles row wid*3+g, li = lane%20 owns
// classes {2li, 2li+1} packed in one uint. 8-edge unroll (24 gathers in
// flight per wave).
__global__ __launch_bounds__(256) void k_spmm2_lsm(
    const int* __restrict__ row_ptr, const int* __restrict__ col,
    const float* __restrict__ val, const unsigned int* __restrict__ sup2,
    const float* __restrict__ b2, float* __restrict__ out, int nrows)
{
    const int wid  = (blockIdx.x * blockDim.x + threadIdx.x) >> 6;
    const int lane = threadIdx.x & 63;
    const int g    = lane / 20;            // 0..2 valid, 3 = idle lanes 60-63
    const int li   = lane - g * 20;
    const int r    = wid * 3 + g;
    const bool active = (g < 3) && (r < nrows);

    int e0 = 0, e1 = 0;
    if (active) { e0 = row_ptr[r]; e1 = row_ptr[r + 1]; }

    float ax = 0.f, ay = 0.f;
    int e = e0;
    for (; e + 7 < e1; e += 8) {
        const int c0 = col[e],   c1 = col[e+1], c2 = col[e+2], c3 = col[e+3];
        const int c4 = col[e+4], c5 = col[e+5], c6 = col[e+6], c7 = col[e+7];
        const float v0 = val[e],   v1 = val[e+1], v2 = val[e+2], v3 = val[e+3];
        const float v4 = val[e+4], v5 = val[e+5], v6 = val[e+6], v7 = val[e+7];
        const unsigned int u0 = sup2[(unsigned)(c0 * 20) + li];
        const unsigned int u1 = sup2[(unsigned)(c1 * 20) + li];
        const unsigned int u2 = sup2[(unsigned)(c2 * 20) + li];
        const unsigned int u3 = sup2[(unsigned)(c3 * 20) + li];
        const unsigned int u4 = sup2[(unsigned)(c4 * 20) + li];
        const unsigned int u5 = sup2[(unsigned)(c5 * 20) + li];
        const unsigned int u6 = sup2[(unsigned)(c6 * 20) + li];
        const unsigned int u7 = sup2[(unsigned)(c7 * 20) + li];
        ax = fmaf(v0, blo(u0), ax); ay = fmaf(v0, bhi(u0), ay);
        ax = fmaf(v1, blo(u1), ax); ay = fmaf(v1, bhi(u1), ay);
        ax = fmaf(v2, blo(u2), ax); ay = fmaf(v2, bhi(u2), ay);
        ax = fmaf(v3, blo(u3), ax); ay = fmaf(v3, bhi(u3), ay);
        ax = fmaf(v4, blo(u4), ax); ay = fmaf(v4, bhi(u4), ay);
        ax = fmaf(v5, blo(u5), ax); ay = fmaf(v5, bhi(u5), ay);
        ax = fmaf(v6, blo(u6), ax); ay = fmaf(v6, bhi(u6), ay);
        ax = fmaf(v7, blo(u7), ax); ay = fmaf(v7, bhi(u7), ay);
    }
    for (; e + 3 < e1; e += 4) {
        const int c0 = col[e],   c1 = col[e+1], c2 = col[e+2], c3 = col[e+3];
        const float v0 = val[e], v1 = val[e+1], v2 = val[e+2], v3 = val[e+3];
        const unsigned int u0 = sup2[(unsigned)(c0 * 20) + li];
        const unsigned int u1 = sup2[(unsigned)(c1 * 20) + li];
        const unsigned int u2 = sup2[(unsigned)(c2 * 20) + li];
        const unsigned int u3 = sup2[(unsigned)(c3 * 20) + li];
        ax = fmaf(v0, blo(u0), ax); ay = fmaf(v0, bhi(u0), ay);
        ax = fmaf(v1, blo(u1), ax); ay = fmaf(v1, bhi(u1), ay);
        ax = fmaf(v2, blo(u2), ax); ay = fmaf(v2, bhi(u2), ay);
        ax = fmaf(v3, blo(u3), ax); ay = fmaf(v3, bhi(u3), ay);
    }
    for (; e < e1; e++) {
        const unsigned int u = sup2[(unsigned)(col[e] * 20) + li];
        const float v = val[e];
        ax = fmaf(v, blo(u), ax); ay = fmaf(v, bhi(u), ay);
    }

    float l0 = -INFINITY, l1 = -INFINITY;
    if (active) {
        l0 = ax + b2[li * 2];
        l1 = ay + b2[li * 2 + 1];
    }

    // group-local (20-lane) shuffle reductions
    float m = fmaxf(l0, l1);
#pragma unroll
    for (int off = 16; off >= 1; off >>= 1) {
        const float t = __shfl_down(m, off, 64);
        if (li + off < 20) m = fmaxf(m, t);
    }
    m = __shfl(m, g * 20, 64);   // broadcast group max

    float s = active ? (__expf(l0 - m) + __expf(l1 - m)) : 0.f;
#pragma unroll
    for (int off = 16; off >= 1; off >>= 1) {
        const float t = __shfl_down(s, off, 64);
        if (li + off < 20) s += t;
    }
    s = __shfl(s, g * 20, 64);

    if (active) {
        const float lse = m + __logf(s);
        float* p = out + (size_t)r * GCN_NCLASS + li * 2;
        p[0] = l0 - lse;
        p[1] = l1 - lse;
    }
}

// ---------------------------------------------------------------------------
extern "C" void kernel_launch(void* const* d_in, const int* in_sizes, int n_in,
                              void* d_out, int out_size, void* d_ws, size_t ws_size,
                              hipStream_t stream)
{
    const float* x       = (const float*)d_in[0];
    const int*   adj_row = (const int*)  d_in[1];
    const int*   adj_col = (const int*)  d_in[2];
    const float* adj_val = (const float*)d_in[3];
    // d_in[4] = i (unused)
    const float* W1 = (const float*)d_in[5];
    const float* b1 = (const float*)d_in[6];
    const float* W2 = (const float*)d_in[7];
    const float* b2 = (const float*)d_in[8];
    float* out = (float*)d_out;

    const int N = in_sizes[0] / GCN_NFEAT;   // 100000
    const int E = in_sizes[1];               // 3200000

    // workspace layout (1 KiB aligned chunks)
    char* ws = (char*)d_ws;
    size_t off = 0;
    int* row_ptr = (int*)(ws + off);
    off += (((size_t)(N + 1) * sizeof(int)) + 1023) & ~(size_t)1023;
    bf16_t* w1t = (bf16_t*)(ws + off);                 // 128*256 bf16
    off += ((size_t)GCN_NHID * GCN_NFEAT * 2 + 1023) & ~(size_t)1023;
    bf16_t* w2t = (bf16_t*)(ws + off);                 // 48*128 bf16
    off += ((size_t)48 * GCN_NHID * 2 + 1023) & ~(size_t)1023;
    bf16_t* sup1 = (bf16_t*)(ws + off);                // N*128 bf16
    off += ((size_t)N * GCN_NHID * 2 + 1023) & ~(size_t)1023;
    bf16_t* h = (bf16_t*)(ws + off);                   // N*128 bf16
    bf16_t* sup2 = sup1;                               // reuse sup1 (N*40 bf16)

    k_row_ptr<<<(N + 1 + 255) / 256, 256, 0, stream>>>(adj_row, row_ptr, N, E);
    k_prep_w1t<<<GCN_NHID * GCN_NFEAT / 256, 256, 0, stream>>>(W1, w1t);
    k_prep_w2t<<<(48 * GCN_NHID + 255) / 256, 256, 0, stream>>>(W2, w2t);
    k_gemm1<<<(N + 127) / 128, 256, 0, stream>>>(x, w1t, sup1, N);
    k_spmm1<<<(N + 3) / 4, 256, 0, stream>>>(row_ptr, adj_col, adj_val,
                                             (const unsigned int*)sup1, b1,
                                             (unsigned int*)h, N);
    k_gemm2<<<(N + 127) / 128, 256, 0, stream>>>(h, w2t, sup2, N);
    const int nw2 = (N + 2) / 3;                       // waves for spmm2
    k_spmm2_lsm<<<(nw2 + 3) / 4, 256, 0, stream>>>(row_ptr, adj_col, adj_val,
                                                   (const unsigned int*)sup2, b2, out, N);
}